// Round 1
// baseline (156.419 us; speedup 1.0000x reference)
//
#include <hip/hip_runtime.h>

#define IMG_W 512
#define IMG_H 512
#define BATCH 64
#define TILE 64
#define LDS_STRIDE 72   // floats per LDS row: [tx0-4, tx0+68)
#define LDS_ROWS 66     // rows: [ty0-1, ty0+65)
#define NBLOCKS (BATCH * 8 * 8)
#define NPIX (BATCH * IMG_W * IMG_H)

__device__ __forceinline__ float fast_sqrtf(float x) {
    return __builtin_amdgcn_sqrtf(x);
}

__global__ __launch_bounds__(256) void sobel_loss_kernel(
    const float* __restrict__ yp, const float* __restrict__ yt,
    float* __restrict__ bsums, float* __restrict__ out_atomic, float inv_n)
{
    __shared__ __align__(16) float ldsP[LDS_ROWS * LDS_STRIDE];
    __shared__ __align__(16) float ldsT[LDS_ROWS * LDS_STRIDE];
    __shared__ float wred[4];

    const int tid = threadIdx.x;
    const int bid = blockIdx.x;
    const int b    = bid >> 6;         // image index
    const int tile = bid & 63;
    const int ty0 = (tile >> 3) * TILE;
    const int tx0 = (tile & 7) * TILE;

    const float* __restrict__ imgp = yp + (size_t)b * (IMG_W * IMG_H);
    const float* __restrict__ imgt = yt + (size_t)b * (IMG_W * IMG_H);

    // ---- Stage halo tile into LDS (float4 granularity) ----
    for (int li = tid; li < LDS_ROWS * 18; li += 256) {
        int r = li / 18;
        int q = li - r * 18;
        int gy = ty0 - 1 + r;
        int gx = tx0 - 4 + (q << 2);
        float4 vp = {0.f, 0.f, 0.f, 0.f};
        float4 vt = {0.f, 0.f, 0.f, 0.f};
        if (gy >= 0 && gy < IMG_H) {
            const float* rowp = imgp + (size_t)gy * IMG_W;
            const float* rowt = imgt + (size_t)gy * IMG_W;
            if (gx >= 0 && gx + 3 < IMG_W) {
                vp = *(const float4*)(rowp + gx);
                vt = *(const float4*)(rowt + gx);
            } else {
                float* ep = &vp.x;
                float* et = &vt.x;
#pragma unroll
                for (int e = 0; e < 4; ++e) {
                    int x = gx + e;
                    if (x >= 0 && x < IMG_W) {
                        ep[e] = rowp[x];
                        et[e] = rowt[x];
                    }
                }
            }
        }
        *(float4*)(&ldsP[r * LDS_STRIDE + (q << 2)]) = vp;
        *(float4*)(&ldsT[r * LDS_STRIDE + (q << 2)]) = vt;
    }
    __syncthreads();

    // ---- Compute: each thread does 4 cols x 4 rows with sliding window ----
    const int px  = (tid & 15) << 2;   // 0..60: output cols px..px+3
    const int ry0 = (tid >> 4) << 2;   // 0..60: output rows ry0..ry0+3

    // three-row rolling window: h = raw values (6 wide), s = 1-2-1 row sums (4 wide)
    float hp[3][6], ht[3][6];
    float sp[3][4], st[3][4];

    auto load_row = [&](int slot, int lr) {
        const float* rp = &ldsP[lr * LDS_STRIDE + px];
        const float* rt = &ldsT[lr * LDS_STRIDE + px];
        float4 v4p = *(const float4*)(rp + 4);
        float4 v4t = *(const float4*)(rt + 4);
        hp[slot][0] = rp[3]; hp[slot][1] = v4p.x; hp[slot][2] = v4p.y;
        hp[slot][3] = v4p.z; hp[slot][4] = v4p.w; hp[slot][5] = rp[8];
        ht[slot][0] = rt[3]; ht[slot][1] = v4t.x; ht[slot][2] = v4t.y;
        ht[slot][3] = v4t.z; ht[slot][4] = v4t.w; ht[slot][5] = rt[8];
#pragma unroll
        for (int j = 0; j < 4; ++j) {
            sp[slot][j] = fmaf(2.f, hp[slot][j + 1], hp[slot][j]) + hp[slot][j + 2];
            st[slot][j] = fmaf(2.f, ht[slot][j + 1], ht[slot][j]) + ht[slot][j + 2];
        }
    };

    load_row(0, ry0);
    load_row(1, ry0 + 1);

    float lsum = 0.f;
#pragma unroll
    for (int i = 0; i < 4; ++i) {
        const int s0 = i % 3, s1 = (i + 1) % 3, s2 = (i + 2) % 3;
        load_row(s2, ry0 + 2 + i);

        // column sums (1-2-1 vertical) for the 6 columns
        float cp[6], ct[6];
#pragma unroll
        for (int k = 0; k < 6; ++k) {
            cp[k] = fmaf(2.f, hp[s1][k], hp[s0][k]) + hp[s2][k];
            ct[k] = fmaf(2.f, ht[s1][k], ht[s0][k]) + ht[s2][k];
        }
#pragma unroll
        for (int j = 0; j < 4; ++j) {
            float ghp = sp[s2][j] - sp[s0][j];
            float gvp = cp[j + 2] - cp[j];
            float magp = fast_sqrtf(fmaf(gvp, gvp, fmaf(ghp, ghp, 1e-18f)));
            float ght = st[s2][j] - st[s0][j];
            float gvt = ct[j + 2] - ct[j];
            float magt = fast_sqrtf(fmaf(gvt, gvt, fmaf(ght, ght, 1e-18f)));
            float d = magt - magp;
            float v = d * d;
            float c = (v == 0.0f) ? 0.0f : fast_sqrtf(v + 1e-18f);
            lsum += c;
        }
    }

    // ---- Block reduction ----
#pragma unroll
    for (int off = 32; off > 0; off >>= 1)
        lsum += __shfl_down(lsum, off, 64);
    const int lane = tid & 63, wid = tid >> 6;
    if (lane == 0) wred[wid] = lsum;
    __syncthreads();
    if (tid == 0) {
        float t = wred[0] + wred[1] + wred[2] + wred[3];
        if (bsums != nullptr) {
            bsums[bid] = t;
        } else {
            atomicAdd(out_atomic, t * inv_n);
        }
    }
}

__global__ __launch_bounds__(256) void reduce_final(
    const float* __restrict__ bsums, float* __restrict__ out)
{
    __shared__ float wred[4];
    const int tid = threadIdx.x;
    float s = 0.f;
    for (int i = tid; i < NBLOCKS; i += 256) s += bsums[i];
#pragma unroll
    for (int off = 32; off > 0; off >>= 1)
        s += __shfl_down(s, off, 64);
    if ((tid & 63) == 0) wred[tid >> 6] = s;
    __syncthreads();
    if (tid == 0)
        out[0] = (wred[0] + wred[1] + wred[2] + wred[3]) * (1.0f / (float)NPIX);
}

__global__ void zero_out_kernel(float* out) { out[0] = 0.f; }

extern "C" void kernel_launch(void* const* d_in, const int* in_sizes, int n_in,
                              void* d_out, int out_size, void* d_ws, size_t ws_size,
                              hipStream_t stream) {
    const float* yp = (const float*)d_in[0];
    const float* yt = (const float*)d_in[1];
    float* out = (float*)d_out;

    if (ws_size >= NBLOCKS * sizeof(float)) {
        float* bsums = (float*)d_ws;
        sobel_loss_kernel<<<NBLOCKS, 256, 0, stream>>>(yp, yt, bsums, nullptr, 0.f);
        reduce_final<<<1, 256, 0, stream>>>(bsums, out);
    } else {
        // Fallback: atomic accumulation directly into d_out
        zero_out_kernel<<<1, 1, 0, stream>>>(out);
        sobel_loss_kernel<<<NBLOCKS, 256, 0, stream>>>(yp, yt, nullptr, out,
                                                       1.0f / (float)NPIX);
    }
}

// Round 2
// 155.101 us; speedup vs baseline: 1.0085x; 1.0085x over previous
//
#include <hip/hip_runtime.h>

#define IMG_W 512
#define IMG_H 512
#define BATCH 64
#define TILE_W 64
#define TILE_H 32
#define LDS_STRIDE 72   // floats per LDS row: [tx0-4, tx0+68)
#define LDS_ROWS 34     // rows: [ty0-1, ty0+33)
#define TILES_X (IMG_W / TILE_W)          // 8
#define TILES_Y (IMG_H / TILE_H)          // 16
#define NBLOCKS (BATCH * TILES_X * TILES_Y)  // 8192
#define NPIX (BATCH * IMG_W * IMG_H)

__device__ __forceinline__ float fast_sqrtf(float x) {
    return __builtin_amdgcn_sqrtf(x);
}

// 19,584 B LDS/block -> 8 blocks/CU; launch_bounds(256,8) pins VGPR <= 64.
__global__ __launch_bounds__(256, 8) void sobel_loss_kernel(
    const float* __restrict__ yp, const float* __restrict__ yt,
    float* __restrict__ bsums)
{
    __shared__ __align__(16) float ldsP[LDS_ROWS * LDS_STRIDE];
    __shared__ __align__(16) float ldsT[LDS_ROWS * LDS_STRIDE];
    __shared__ float wred[4];

    const int tid = threadIdx.x;
    const int bid = blockIdx.x;
    const int b    = bid >> 7;            // image index (128 tiles/image)
    const int tile = bid & 127;
    const int ty0 = (tile >> 3) * TILE_H; // 16 y-tiles
    const int tx0 = (tile & 7) * TILE_W;  // 8 x-tiles

    const float* __restrict__ imgp = yp + (size_t)b * (IMG_W * IMG_H);
    const float* __restrict__ imgt = yt + (size_t)b * (IMG_W * IMG_H);

    // ---- Stage halo tile into LDS (float4 granularity): 34 rows x 18 f4 ----
    for (int li = tid; li < LDS_ROWS * 18; li += 256) {
        int r = li / 18;
        int q = li - r * 18;
        int gy = ty0 - 1 + r;
        int gx = tx0 - 4 + (q << 2);
        float4 vp = {0.f, 0.f, 0.f, 0.f};
        float4 vt = {0.f, 0.f, 0.f, 0.f};
        if (gy >= 0 && gy < IMG_H) {
            const float* rowp = imgp + (size_t)gy * IMG_W;
            const float* rowt = imgt + (size_t)gy * IMG_W;
            if (gx >= 0 && gx + 3 < IMG_W) {
                vp = *(const float4*)(rowp + gx);
                vt = *(const float4*)(rowt + gx);
            } else {
                float* ep = &vp.x;
                float* et = &vt.x;
#pragma unroll
                for (int e = 0; e < 4; ++e) {
                    int x = gx + e;
                    if (x >= 0 && x < IMG_W) {
                        ep[e] = rowp[x];
                        et[e] = rowt[x];
                    }
                }
            }
        }
        *(float4*)(&ldsP[r * LDS_STRIDE + (q << 2)]) = vp;
        *(float4*)(&ldsT[r * LDS_STRIDE + (q << 2)]) = vt;
    }
    __syncthreads();

    // ---- Compute: each thread does 4 cols x 2 rows, rolling 3-row window ----
    const int px  = (tid & 15) << 2;   // output cols px..px+3 (tile-relative)
    const int ry0 = (tid >> 4) << 1;   // output rows ry0..ry0+1

    float hp[3][6], ht[3][6];          // raw values (x-1..x+4)
    float sp[3][4], st[3][4];          // 1-2-1 horizontal sums

    auto load_row = [&](int slot, int lr) {
        const float* rp = &ldsP[lr * LDS_STRIDE + px];
        const float* rt = &ldsT[lr * LDS_STRIDE + px];
        float4 v4p = *(const float4*)(rp + 4);
        float4 v4t = *(const float4*)(rt + 4);
        hp[slot][0] = rp[3]; hp[slot][1] = v4p.x; hp[slot][2] = v4p.y;
        hp[slot][3] = v4p.z; hp[slot][4] = v4p.w; hp[slot][5] = rp[8];
        ht[slot][0] = rt[3]; ht[slot][1] = v4t.x; ht[slot][2] = v4t.y;
        ht[slot][3] = v4t.z; ht[slot][4] = v4t.w; ht[slot][5] = rt[8];
#pragma unroll
        for (int j = 0; j < 4; ++j) {
            sp[slot][j] = fmaf(2.f, hp[slot][j + 1], hp[slot][j]) + hp[slot][j + 2];
            st[slot][j] = fmaf(2.f, ht[slot][j + 1], ht[slot][j]) + ht[slot][j + 2];
        }
    };

    load_row(0, ry0);
    load_row(1, ry0 + 1);

    float lsum = 0.f;
#pragma unroll
    for (int i = 0; i < 2; ++i) {
        const int s0 = i % 3, s1 = (i + 1) % 3, s2 = (i + 2) % 3;
        load_row(s2, ry0 + 2 + i);

        // vertical 1-2-1 column sums for the 6 columns
        float cp[6], ct[6];
#pragma unroll
        for (int k = 0; k < 6; ++k) {
            cp[k] = fmaf(2.f, hp[s1][k], hp[s0][k]) + hp[s2][k];
            ct[k] = fmaf(2.f, ht[s1][k], ht[s0][k]) + ht[s2][k];
        }
#pragma unroll
        for (int j = 0; j < 4; ++j) {
            float ghp = sp[s2][j] - sp[s0][j];
            float gvp = cp[j + 2] - cp[j];
            float magp = fast_sqrtf(fmaf(gvp, gvp, fmaf(ghp, ghp, 1e-18f)));
            float ght = st[s2][j] - st[s0][j];
            float gvt = ct[j + 2] - ct[j];
            float magt = fast_sqrtf(fmaf(gvt, gvt, fmaf(ght, ght, 1e-18f)));
            // reference: sqrt(d^2 + 1e-18) * (d^2 != 0)  ==  |d| to <1e-9 abs
            lsum += fabsf(magt - magp);
        }
    }

    // ---- Block reduction ----
#pragma unroll
    for (int off = 32; off > 0; off >>= 1)
        lsum += __shfl_down(lsum, off, 64);
    const int lane = tid & 63, wid = tid >> 6;
    if (lane == 0) wred[wid] = lsum;
    __syncthreads();
    if (tid == 0)
        bsums[bid] = wred[0] + wred[1] + wred[2] + wred[3];
}

__global__ __launch_bounds__(256) void reduce_final(
    const float* __restrict__ bsums, float* __restrict__ out)
{
    __shared__ float wred[4];
    const int tid = threadIdx.x;
    float s = 0.f;
    for (int i = tid; i < NBLOCKS; i += 256) s += bsums[i];
#pragma unroll
    for (int off = 32; off > 0; off >>= 1)
        s += __shfl_down(s, off, 64);
    if ((tid & 63) == 0) wred[tid >> 6] = s;
    __syncthreads();
    if (tid == 0)
        out[0] = (wred[0] + wred[1] + wred[2] + wred[3]) * (1.0f / (float)NPIX);
}

__global__ void zero_out_kernel(float* out) { out[0] = 0.f; }

__global__ __launch_bounds__(256, 8) void sobel_loss_kernel_atomic(
    const float* __restrict__ yp, const float* __restrict__ yt,
    float* __restrict__ out, float inv_n);

extern "C" void kernel_launch(void* const* d_in, const int* in_sizes, int n_in,
                              void* d_out, int out_size, void* d_ws, size_t ws_size,
                              hipStream_t stream) {
    const float* yp = (const float*)d_in[0];
    const float* yt = (const float*)d_in[1];
    float* out = (float*)d_out;

    float* bsums = (float*)d_ws;   // needs 32 KB; ws_size was sufficient in R0
    sobel_loss_kernel<<<NBLOCKS, 256, 0, stream>>>(yp, yt, bsums);
    reduce_final<<<1, 256, 0, stream>>>(bsums, out);
}